// Round 1
// baseline (465.099 us; speedup 1.0000x reference)
//
#include <hip/hip_runtime.h>
#include <math.h>

#define BB 128
#define CC 512
#define HW 1024
#define EE 16
#define KK 2
#define INV_NOISE_STD 16.0f
#define EPSV 1e-8f

typedef float vf4 __attribute__((ext_vector_type(4)));

__device__ __forceinline__ float wave_sum(float v) {
    #pragma unroll
    for (int off = 32; off > 0; off >>= 1) v += __shfl_down(v, off, 64);
    return v;
}

// Kernel A: pooled[p] = mean over 1024 contiguous floats. One wave per (b,c).
// Nontemporal streaming reads: x is 256 MB with zero reuse. This is the
// mandatory-traffic kernel (~40 us at ~6.4 TB/s); shape unchanged.
__global__ void __launch_bounds__(256) pool_kernel(const float* __restrict__ x,
                                                   float* __restrict__ pooled) {
    int wave = (blockIdx.x * 256 + threadIdx.x) >> 6;   // global (b*C+c)
    int lane = threadIdx.x & 63;
    const vf4* p = (const vf4*)(x + (size_t)wave * HW);
    float s = 0.0f;
    #pragma unroll
    for (int j = 0; j < 4; ++j) {
        vf4 v = __builtin_nontemporal_load(&p[lane + 64 * j]);
        s += (v.x + v.y) + (v.z + v.w);
    }
    s = wave_sum(s);
    if (lane == 0) pooled[wave] = s * (1.0f / 1024.0f);
}

// Fused kernel B+C: logits + all statistics + outputs in ONE block of 1024
// threads. Logits phase processes 4 batch rows per pass with the EXACT same
// per-(b,e) 16-lane strided dot + shfl tree as the old logits_kernel, so
// results are bit-identical. Logits live in LDS (no global round-trip).
__global__ void __launch_bounds__(1024) fused_kernel(const float* __restrict__ pooled,
                                                     const float* __restrict__ Wg,
                                                     const float* __restrict__ complexity,
                                                     const float* __restrict__ noise,
                                                     float* __restrict__ out) {
    // out layout: gates[B*E] | idx[B*K] | vals[B*K] | aux[1]
    __shared__ float lsm[BB * EE];     // 8 KB: all logits
    __shared__ float prow[4 * CC];     // 8 KB: 4 staged pooled rows
    __shared__ float imp[EE];
    __shared__ float psum[EE];
    int t = threadIdx.x;

    if (t < EE) { imp[t] = 0.0f; psum[t] = 0.0f; }

    // ---- Phase A: logits, 4 rows per pass (32 passes) ----
    int sub = t >> 8;      // which of the 4 row-slots (0..3)
    int tt  = t & 255;     // same mapping as old 256-thread logits_kernel
    int e   = tt >> 4;     // 0..15
    int g   = tt & 15;     // 0..15
    for (int b0 = 0; b0 < BB; b0 += 4) {
        // stage 4 pooled rows (2048 floats) with 1024 threads
        for (int c = t; c < 4 * CC; c += 1024)
            prow[c] = pooled[(size_t)b0 * CC + c];
        __syncthreads();
        float s = 0.0f;
        for (int c = g; c < CC; c += 16) s += prow[sub * CC + c] * Wg[e * CC + c];
        #pragma unroll
        for (int off = 8; off > 0; off >>= 1) s += __shfl_down(s, off, 16);
        if (g == 0) lsm[(b0 + sub) * EE + e] = s;
        __syncthreads();   // protect prow reuse next pass; also publishes lsm
    }

    // ---- Phase B: stats, threads 0..127 (waves 0 and 1, wave-aligned) ----
    if (t < BB) {
        int b = t;
        int lane = t & 63;
        float lg[EE], nlg[EE];
        #pragma unroll
        for (int e2 = 0; e2 < EE; ++e2) lg[e2] = lsm[b * EE + e2];
        #pragma unroll
        for (int e2 = 0; e2 < EE; ++e2) nlg[e2] = lg[e2] + noise[b * EE + e2];

        // softmax(logits) -> importance accumulation
        float mx = lg[0];
        #pragma unroll
        for (int e2 = 1; e2 < EE; ++e2) mx = fmaxf(mx, lg[e2]);
        float sm[EE]; float se = 0.0f;
        #pragma unroll
        for (int e2 = 0; e2 < EE; ++e2) { sm[e2] = expf(lg[e2] - mx); se += sm[e2]; }
        float inv_se = 1.0f / se;
        #pragma unroll
        for (int e2 = 0; e2 < EE; ++e2) {
            float ws = wave_sum(sm[e2] * inv_se);
            if (lane == 0) atomicAdd(&imp[e2], ws);
        }

        // softmax(noisy logits) -> gating scores; top-2 (lowest-index tie-break)
        float mxn = nlg[0];
        #pragma unroll
        for (int e2 = 1; e2 < EE; ++e2) mxn = fmaxf(mxn, nlg[e2]);
        float gsc[EE]; float sen = 0.0f;
        #pragma unroll
        for (int e2 = 0; e2 < EE; ++e2) { gsc[e2] = expf(nlg[e2] - mxn); sen += gsc[e2]; }
        float inv_sen = 1.0f / sen;
        #pragma unroll
        for (int e2 = 0; e2 < EE; ++e2) gsc[e2] *= inv_sen;

        int i1 = 0;
        #pragma unroll
        for (int e2 = 1; e2 < EE; ++e2) if (nlg[e2] > nlg[i1]) i1 = e2;
        int i2 = (i1 == 0) ? 1 : 0;
        #pragma unroll
        for (int e2 = 0; e2 < EE; ++e2) if (e2 != i1 && e2 != i2 && nlg[e2] > nlg[i2]) i2 = e2;
        float thr = nlg[i2];
        float v1 = gsc[i1], v2 = gsc[i2];

        // load-balance probability p[e] = 0.5*erfc((thr - lg[e]) * 16 / sqrt(2))
        #pragma unroll
        for (int e2 = 0; e2 < EE; ++e2) {
            float z = (thr - lg[e2]) * INV_NOISE_STD;
            float p = 0.5f * erfcf(z * 0.70710678118654752f);
            float ws = wave_sum(p);
            if (lane == 0) atomicAdd(&psum[e2], ws);
        }

        // dense gates + top-k outputs
        #pragma unroll
        for (int e2 = 0; e2 < EE; ++e2)
            out[b * EE + e2] = (e2 == i1) ? v1 : ((e2 == i2) ? v2 : 0.0f);
        out[BB * EE + b * KK + 0] = (float)i1;
        out[BB * EE + b * KK + 1] = (float)i2;
        out[BB * EE + BB * KK + b * KK + 0] = v1;
        out[BB * EE + BB * KK + b * KK + 1] = v2;
    }

    __syncthreads();
    if (t == 0) {
        float im[EE]; float mean1 = 0.0f;
        #pragma unroll
        for (int e2 = 0; e2 < EE; ++e2) { im[e2] = imp[e2] * complexity[e2]; mean1 += im[e2]; }
        mean1 *= (1.0f / EE);
        float var1 = 0.0f;
        #pragma unroll
        for (int e2 = 0; e2 < EE; ++e2) { float d = im[e2] - mean1; var1 += d * d; }
        var1 *= (1.0f / (EE - 1));
        float li = var1 / ((mean1 + EPSV) * (mean1 + EPSV));

        float pm[EE]; float mean2 = 0.0f;
        #pragma unroll
        for (int e2 = 0; e2 < EE; ++e2) { pm[e2] = psum[e2] * (1.0f / BB); mean2 += pm[e2]; }
        mean2 *= (1.0f / EE);
        float var2 = 0.0f;
        #pragma unroll
        for (int e2 = 0; e2 < EE; ++e2) { float d = pm[e2] - mean2; var2 += d * d; }
        var2 *= (1.0f / (EE - 1));
        float ll = var2 / ((mean2 + EPSV) * (mean2 + EPSV));

        out[BB * EE + 2 * BB * KK] = 0.5f * li + 0.5f * ll;
    }
}

extern "C" void kernel_launch(void* const* d_in, const int* in_sizes, int n_in,
                              void* d_out, int out_size, void* d_ws, size_t ws_size,
                              hipStream_t stream) {
    const float* x     = (const float*)d_in[0];   // [128,512,32,32]
    const float* Wg    = (const float*)d_in[1];   // [16,512]
    const float* comp  = (const float*)d_in[2];   // [16]
    const float* noise = (const float*)d_in[3];   // [128,16]
    float* out = (float*)d_out;

    float* pooled = (float*)d_ws;          // B*C = 65536 floats

    pool_kernel<<<(BB * CC) / 4, 256, 0, stream>>>(x, pooled);
    fused_kernel<<<1, 1024, 0, stream>>>(pooled, Wg, comp, noise, out);
}

// Round 2
// 356.842 us; speedup vs baseline: 1.3034x; 1.3034x over previous
//
#include <hip/hip_runtime.h>
#include <math.h>

#define BB 128
#define CC 512
#define HW 1024
#define EE 16
#define KK 2
#define INV_NOISE_STD 16.0f
#define EPSV 1e-8f

typedef float vf4 __attribute__((ext_vector_type(4)));

__device__ __forceinline__ float wave_sum(float v) {
    #pragma unroll
    for (int off = 32; off > 0; off >>= 1) v += __shfl_down(v, off, 64);
    return v;
}

// Kernel A: pooled[p] = mean over 1024 contiguous floats. One wave per (b,c).
// Nontemporal streaming reads: x is 256 MB with zero reuse. Mandatory-traffic
// kernel: 256 MiB / ~6.7 TB/s ~= 38 us (HBM roofline).
__global__ void __launch_bounds__(256) pool_kernel(const float* __restrict__ x,
                                                   float* __restrict__ pooled) {
    int wave = (blockIdx.x * 256 + threadIdx.x) >> 6;   // global (b*C+c)
    int lane = threadIdx.x & 63;
    const vf4* p = (const vf4*)(x + (size_t)wave * HW);
    float s = 0.0f;
    #pragma unroll
    for (int j = 0; j < 4; ++j) {
        vf4 v = __builtin_nontemporal_load(&p[lane + 64 * j]);
        s += (v.x + v.y) + (v.z + v.w);
    }
    s = wave_sum(s);
    if (lane == 0) pooled[wave] = s * (1.0f / 1024.0f);
}

// Kernel B: logits[b,e] = dot(pooled[b,:], W_gate[e,:]). One block per b
// (128 blocks -> 128 CUs in parallel). NOTE: do NOT fuse this into a single
// block — round-1 experiment put ~1M Wg loads on one CU and cost +109 us.
__global__ void __launch_bounds__(256) logits_kernel(const float* __restrict__ pooled,
                                                     const float* __restrict__ Wg,
                                                     float* __restrict__ logits) {
    __shared__ float prow[CC];
    int b = blockIdx.x;
    for (int c = threadIdx.x; c < CC; c += 256) prow[c] = pooled[b * CC + c];
    __syncthreads();
    int t = threadIdx.x;
    int e = t >> 4;      // 0..15
    int g = t & 15;      // 0..15
    float s = 0.0f;
    for (int c = g; c < CC; c += 16) s += prow[c] * Wg[e * CC + c];
    #pragma unroll
    for (int off = 8; off > 0; off >>= 1) s += __shfl_down(s, off, 16);
    if (g == 0) logits[b * EE + e] = s;
}

// Kernel C: all statistics + outputs. Single block, 128 threads (1 per batch row).
__global__ void __launch_bounds__(128) stats_kernel(const float* __restrict__ logits,
                                                    const float* __restrict__ complexity,
                                                    const float* __restrict__ noise,
                                                    float* __restrict__ out) {
    // out layout: gates[B*E] | idx[B*K] | vals[B*K] | aux[1]
    __shared__ float imp[EE];
    __shared__ float psum[EE];
    int t = threadIdx.x;
    int lane = t & 63;
    if (t < EE) { imp[t] = 0.0f; psum[t] = 0.0f; }
    __syncthreads();

    int b = t;
    float lg[EE], nlg[EE];
    #pragma unroll
    for (int e = 0; e < EE; ++e) lg[e] = logits[b * EE + e];
    #pragma unroll
    for (int e = 0; e < EE; ++e) nlg[e] = lg[e] + noise[b * EE + e];

    // softmax(logits) -> importance accumulation
    float mx = lg[0];
    #pragma unroll
    for (int e = 1; e < EE; ++e) mx = fmaxf(mx, lg[e]);
    float sm[EE]; float se = 0.0f;
    #pragma unroll
    for (int e = 0; e < EE; ++e) { sm[e] = expf(lg[e] - mx); se += sm[e]; }
    float inv_se = 1.0f / se;
    #pragma unroll
    for (int e = 0; e < EE; ++e) {
        float ws = wave_sum(sm[e] * inv_se);
        if (lane == 0) atomicAdd(&imp[e], ws);
    }

    // softmax(noisy logits) -> gating scores; top-2 (lowest-index tie-break)
    float mxn = nlg[0];
    #pragma unroll
    for (int e = 1; e < EE; ++e) mxn = fmaxf(mxn, nlg[e]);
    float gsc[EE]; float sen = 0.0f;
    #pragma unroll
    for (int e = 0; e < EE; ++e) { gsc[e] = expf(nlg[e] - mxn); sen += gsc[e]; }
    float inv_sen = 1.0f / sen;
    #pragma unroll
    for (int e = 0; e < EE; ++e) gsc[e] *= inv_sen;

    int i1 = 0;
    #pragma unroll
    for (int e = 1; e < EE; ++e) if (nlg[e] > nlg[i1]) i1 = e;
    int i2 = (i1 == 0) ? 1 : 0;
    #pragma unroll
    for (int e = 0; e < EE; ++e) if (e != i1 && e != i2 && nlg[e] > nlg[i2]) i2 = e;
    float thr = nlg[i2];
    float v1 = gsc[i1], v2 = gsc[i2];

    // load-balance probability p[e] = 0.5*erfc((thr - lg[e]) * 16 / sqrt(2))
    #pragma unroll
    for (int e = 0; e < EE; ++e) {
        float z = (thr - lg[e]) * INV_NOISE_STD;
        float p = 0.5f * erfcf(z * 0.70710678118654752f);
        float ws = wave_sum(p);
        if (lane == 0) atomicAdd(&psum[e], ws);
    }

    // dense gates + top-k outputs
    #pragma unroll
    for (int e = 0; e < EE; ++e)
        out[b * EE + e] = (e == i1) ? v1 : ((e == i2) ? v2 : 0.0f);
    out[BB * EE + b * KK + 0] = (float)i1;
    out[BB * EE + b * KK + 1] = (float)i2;
    out[BB * EE + BB * KK + b * KK + 0] = v1;
    out[BB * EE + BB * KK + b * KK + 1] = v2;

    __syncthreads();
    if (t == 0) {
        float im[EE]; float mean1 = 0.0f;
        #pragma unroll
        for (int e = 0; e < EE; ++e) { im[e] = imp[e] * complexity[e]; mean1 += im[e]; }
        mean1 *= (1.0f / EE);
        float var1 = 0.0f;
        #pragma unroll
        for (int e = 0; e < EE; ++e) { float d = im[e] - mean1; var1 += d * d; }
        var1 *= (1.0f / (EE - 1));
        float li = var1 / ((mean1 + EPSV) * (mean1 + EPSV));

        float pm[EE]; float mean2 = 0.0f;
        #pragma unroll
        for (int e = 0; e < EE; ++e) { pm[e] = psum[e] * (1.0f / BB); mean2 += pm[e]; }
        mean2 *= (1.0f / EE);
        float var2 = 0.0f;
        #pragma unroll
        for (int e = 0; e < EE; ++e) { float d = pm[e] - mean2; var2 += d * d; }
        var2 *= (1.0f / (EE - 1));
        float ll = var2 / ((mean2 + EPSV) * (mean2 + EPSV));

        out[BB * EE + 2 * BB * KK] = 0.5f * li + 0.5f * ll;
    }
}

extern "C" void kernel_launch(void* const* d_in, const int* in_sizes, int n_in,
                              void* d_out, int out_size, void* d_ws, size_t ws_size,
                              hipStream_t stream) {
    const float* x     = (const float*)d_in[0];   // [128,512,32,32]
    const float* Wg    = (const float*)d_in[1];   // [16,512]
    const float* comp  = (const float*)d_in[2];   // [16]
    const float* noise = (const float*)d_in[3];   // [128,16]
    float* out = (float*)d_out;

    float* pooled = (float*)d_ws;          // B*C = 65536 floats
    float* logits = pooled + BB * CC;      // B*E = 2048 floats

    pool_kernel<<<(BB * CC) / 4, 256, 0, stream>>>(x, pooled);
    logits_kernel<<<BB, 256, 0, stream>>>(pooled, Wg, logits);
    stats_kernel<<<1, 128, 0, stream>>>(logits, comp, noise, out);
}